// Round 4
// baseline (275.182 us; speedup 1.0000x reference)
//
#include <hip/hip_runtime.h>
#include <math.h>

// Problem constants (from reference: B=8, T=4096, D=1024, fp32)
#define BB 8
#define TT 4096
#define DD 1024
#define NC 256            // number of T-chunks per batch
#define CT (TT / NC)      // chunk length = 16
#define D4 (DD / 4)       // float4s per row = 256
#define SCW 16            // chunks per superchunk
#define SC (NC / SCW)     // superchunks per batch = 16

// ws layout (floats):
//   [0,          BB*NC*DD)      per-chunk aggregates agg[B][NC][D]   (8 MB)
//   [BB*NC*DD,   +BB*SC*DD)     exclusive superchunk prefix P[B][SC][D] (512 KB)
#define AGG_OFF 0
#define PFX_OFF (BB * NC * DD)

typedef float vfloat4 __attribute__((ext_vector_type(4)));

__device__ __forceinline__ float gelu_exact(float v) {
    // exact GELU: 0.5*v*(1+erf(v/sqrt(2)))
    return 0.5f * v * (1.0f + erff(v * 0.70710678118654752f));
}

__device__ __forceinline__ void gelu_acc(float4& s, const float4 v) {
    s.x += gelu_exact(v.x);
    s.y += gelu_exact(v.y);
    s.z += gelu_exact(v.z);
    s.w += gelu_exact(v.w);
}

__device__ __forceinline__ void f4_acc(float4& s, const float4 a) {
    s.x += a.x; s.y += a.y; s.z += a.z; s.w += a.w;
}

// ---------------------------------------------------------------------------
// K1: per-(b,chunk) masked gelu aggregate. ALWAYS stores (zeros for fully
// masked chunks) so K1.5/K2 can read unconditionally. 2048 blocks.
// ---------------------------------------------------------------------------
__global__ __launch_bounds__(256)
void k_partial(const float* __restrict__ x, const int* __restrict__ lengths,
               float* __restrict__ ws) {
    const int c  = blockIdx.x;
    const int b  = blockIdx.y;
    const int d4 = threadIdx.x;
    const int len = lengths[b];
    const int t0 = c * CT;
    const int t1 = min(t0 + CT, len);   // may be <= t0 (fully masked)

    const float4* __restrict__ xp = (const float4*)(x + (size_t)b * TT * DD);
    float4 s = make_float4(0.f, 0.f, 0.f, 0.f);
    #pragma unroll 4
    for (int t = t0; t < t1; ++t) {
        float4 v = xp[(size_t)t * D4 + d4];
        gelu_acc(s, v);
    }
    // regular (cached) store — re-read by K1.5/K2 from L2
    ((float4*)(ws + AGG_OFF))[((size_t)b * NC + c) * D4 + d4] = s;
}

// ---------------------------------------------------------------------------
// K1.5: exclusive superchunk prefix P[b][s] = sum_{cc < s*SCW} agg[b][cc].
// 128 blocks, pure L2 traffic (~61 MB total), ~3 us. Two accumulators keep
// 8+ independent coalesced 1KB/wave loads in flight.
// ---------------------------------------------------------------------------
__global__ __launch_bounds__(256)
void k_sprefix(float* __restrict__ ws) {
    const int s  = blockIdx.x;      // superchunk
    const int b  = blockIdx.y;
    const int d4 = threadIdx.x;
    const int n  = s * SCW;         // number of preceding chunks

    const float4* __restrict__ aggp =
        (const float4*)(ws + AGG_OFF) + (size_t)b * NC * D4 + d4;
    float4 p0 = make_float4(0.f, 0.f, 0.f, 0.f);
    float4 p1 = make_float4(0.f, 0.f, 0.f, 0.f);
    int cc = 0;
    #pragma unroll 4
    for (; cc + 1 < n; cc += 2) {
        float4 a0 = aggp[(size_t)cc * D4];
        float4 a1 = aggp[(size_t)(cc + 1) * D4];
        f4_acc(p0, a0);
        f4_acc(p1, a1);
    }
    if (cc < n) f4_acc(p0, aggp[(size_t)cc * D4]);
    f4_acc(p0, p1);
    ((float4*)(ws + PFX_OFF))[((size_t)b * SC + s) * D4 + d4] = p0;
}

// ---------------------------------------------------------------------------
// K2: exclusive chunk prefix = P[b][c/SCW] + (<=15 same-superchunk aggs),
// then apply: re-read x rows (L3-warm), running gelu prefix, NT-store out.
// 2048 blocks, lookback is <=16 float4 loads/thread (vs <=255 in R2).
// ---------------------------------------------------------------------------
__global__ __launch_bounds__(256)
void k_apply(const float* __restrict__ x, const int* __restrict__ lengths,
             const float* __restrict__ ws, float* __restrict__ out) {
    const int c  = blockIdx.x;
    const int b  = blockIdx.y;
    const int d4 = threadIdx.x;
    const int len = lengths[b];
    const int t0 = c * CT;
    const int tv = min(t0 + CT, len);

    const float4* __restrict__ xp = (const float4*)(x + (size_t)b * TT * DD);
    vfloat4* __restrict__ op = (vfloat4*)(out + (size_t)b * TT * DD);

    int t = t0;
    if (t0 < len) {
        const int sc = c / SCW;
        float4 pre =
            ((const float4*)(ws + PFX_OFF))[((size_t)b * SC + sc) * D4 + d4];

        const float4* __restrict__ aggp =
            (const float4*)(ws + AGG_OFF) + (size_t)b * NC * D4 + d4;
        float4 p1 = make_float4(0.f, 0.f, 0.f, 0.f);
        int cc = sc * SCW;
        #pragma unroll 4
        for (; cc + 1 < c; cc += 2) {
            float4 a0 = aggp[(size_t)cc * D4];
            float4 a1 = aggp[(size_t)(cc + 1) * D4];
            f4_acc(pre, a0);
            f4_acc(p1, a1);
        }
        if (cc < c) f4_acc(pre, aggp[(size_t)cc * D4]);
        f4_acc(pre, p1);

        // ---- apply: running inclusive prefix over the chunk ----
        #pragma unroll 4
        for (; t < tv; ++t) {
            float4 v = xp[(size_t)t * D4 + d4];
            gelu_acc(pre, v);
            vfloat4 o = {v.x + pre.x, v.y + pre.y, v.z + pre.z, v.w + pre.w};
            __builtin_nontemporal_store(o, &op[(size_t)t * D4 + d4]);
        }
    }
    // rows at/after length: plain copy (mask is 0)
    #pragma unroll 4
    for (; t < t0 + CT; ++t) {
        float4 v = xp[(size_t)t * D4 + d4];
        vfloat4 o = {v.x, v.y, v.z, v.w};
        __builtin_nontemporal_store(o, &op[(size_t)t * D4 + d4]);
    }
}

extern "C" void kernel_launch(void* const* d_in, const int* in_sizes, int n_in,
                              void* d_out, int out_size, void* d_ws, size_t ws_size,
                              hipStream_t stream) {
    const float* x       = (const float*)d_in[0];
    const int*   lengths = (const int*)d_in[1];
    float*       out     = (float*)d_out;
    float*       ws      = (float*)d_ws;   // needs (BB*NC*DD + BB*SC*DD)*4 = 8.5 MB

    dim3 blk(256, 1, 1);
    dim3 g1(NC, BB, 1);
    hipLaunchKernelGGL(k_partial, g1, blk, 0, stream, x, lengths, ws);

    dim3 g15(SC, BB, 1);   // 128 blocks
    hipLaunchKernelGGL(k_sprefix, g15, blk, 0, stream, ws);

    hipLaunchKernelGGL(k_apply, g1, blk, 0, stream, x, lengths, ws, out);
}